// Round 7
// baseline (243.198 us; speedup 1.0000x reference)
//
#include <hip/hip_runtime.h>

typedef _Float16 half_t;
typedef __attribute__((ext_vector_type(8))) _Float16 half8;
typedef __attribute__((ext_vector_type(4))) _Float16 half4;
typedef __attribute__((ext_vector_type(4))) float f32x4;

#define SEQ   2048
#define DM    1024
#define NH    16
#define DEPTH 64

__device__ __forceinline__ void gload16(const void* g, void* l) {
    __builtin_amdgcn_global_load_lds(
        (const __attribute__((address_space(1))) void*)g,
        (__attribute__((address_space(3))) void*)l, 16, 0, 0);
}

// ---------------- weight transpose + fp32->fp16 ----------------
__global__ __launch_bounds__(256) void wtrans_k(
    const float* __restrict__ w0, const float* __restrict__ w1,
    const float* __restrict__ w2, const float* __restrict__ w3,
    half_t* __restrict__ out)
{
    __shared__ float tile[32][33];
    const float* srcs[4] = {w0, w1, w2, w3};
    const float* src = srcs[blockIdx.z];
    half_t* dst = out + (size_t)blockIdx.z * DM * DM;
    int n0 = blockIdx.x * 32, k0 = blockIdx.y * 32;
    int tx = threadIdx.x, ty = threadIdx.y;
#pragma unroll
    for (int i = 0; i < 4; ++i)
        tile[ty + 8*i][tx] = src[(size_t)(k0 + ty + 8*i)*DM + n0 + tx];
    __syncthreads();
#pragma unroll
    for (int i = 0; i < 4; ++i)
        dst[(size_t)(n0 + ty + 8*i)*DM + k0 + tx] = (half_t)tile[tx][ty + 8*i];
}

// ---------------- mask compaction: posv/cnt + Kc pad-zero ----------------
// 1 block, 4 waves; wave b: posv[b*SEQ+s] = compacted pos (or -1 if masked),
// cnt[b] = count; then zeroes Kc pad rows cnt..roundup64(cnt)-1 (NaN safety:
// scatter never writes them, and the attn tail tile does MFMA on them).
__global__ __launch_bounds__(256) void midx_k(const int* __restrict__ mask,
    int* __restrict__ posv, int* __restrict__ cnt, half_t* __restrict__ Kc)
{
    const int b = threadIdx.x >> 6;
    const int lane = threadIdx.x & 63;
    const int* m = mask + b*SEQ;
    int off = 0;
    for (int c = 0; c < SEQ; c += 64) {
        int keep = (m[c + lane] == 0);
        unsigned long long bal = __ballot(keep);
        int pre = __popcll(bal & ((1ull << lane) - 1ull));
        posv[b*SEQ + c + lane] = keep ? (off + pre) : -1;
        off += __popcll(bal);
    }
    if (lane == 0) cnt[b] = off;
    const int end = (off + 63) & ~63;
    half8 z = {};
    for (int r = off; r < end; ++r) {
#pragma unroll
        for (int c8 = lane; c8 < 128; c8 += 64)
            *(half8*)(Kc + ((size_t)(b*SEQ + r))*DM + c8*8) = z;
    }
}

// ---------------- fused Q/K/V projection (cvt folded, scatter for K/V) ----------------
// z=0: Qh = qscale*(q@wq+bq) linear ; z=1: Kc[pos] = k@wk+bk scatter ;
// z=2: Vc[pos] = v@wv+bv scatter. A staged f32->f16 in-register; B via gload16.
__global__ __launch_bounds__(256) void qkv_proj(
    const float* __restrict__ Aq, const float* __restrict__ Ak, const float* __restrict__ Av,
    const half_t* __restrict__ wT,
    const float* __restrict__ bq, const float* __restrict__ bk, const float* __restrict__ bv,
    const int* __restrict__ posv,
    half_t* __restrict__ Qh, half_t* __restrict__ Kc, half_t* __restrict__ Vc,
    float qscale)
{
    __shared__ __align__(16) half_t lA[128*64];
    __shared__ __align__(16) half_t lB[128*64];
    const int z = blockIdx.z;
    const float* Af   = (z == 0) ? Aq : (z == 1) ? Ak : Av;
    const half_t* Bt  = wT + (size_t)z * DM * DM;
    const float* bias = (z == 0) ? bq : (z == 1) ? bk : bv;

    const int t = threadIdx.x, lane = t & 63, wave = t >> 6;
    const int wr = wave >> 1, wc = wave & 1;
    const int m0 = blockIdx.y * 128, n0 = blockIdx.x * 128;
    const int lr = lane & 15, lq = lane >> 4;
    const int srow = lane >> 3, scol = (lane & 7) * 8;

    f32x4 acc[4][4] = {};

    for (int k0 = 0; k0 < DM; k0 += 64) {
        __syncthreads();
        // B tile via async global->LDS
#pragma unroll
        for (int i = 0; i < 4; ++i) {
            const int chunk = wave*4 + i;                 // wave-uniform
            const int row = chunk*8 + srow;
            gload16(Bt + (size_t)(n0+row)*DM + k0 + scol, lB + chunk*512);
        }
        // A tile: reg-stage f32 -> f16 (4 granules of 8 halves per thread)
#pragma unroll
        for (int i = 0; i < 4; ++i) {
            const int g = i*256 + t;
            const int row = g >> 3, sl = (g & 7) * 8;
            const float* ap = Af + (size_t)(m0+row)*DM + k0 + sl;
            float4 lo = *(const float4*)ap;
            float4 hi = *(const float4*)(ap + 4);
            half8 h8;
            h8[0]=(half_t)lo.x; h8[1]=(half_t)lo.y; h8[2]=(half_t)lo.z; h8[3]=(half_t)lo.w;
            h8[4]=(half_t)hi.x; h8[5]=(half_t)hi.y; h8[6]=(half_t)hi.z; h8[7]=(half_t)hi.w;
            *(half8*)(lA + row*64 + sl) = h8;
        }
        __syncthreads();

#pragma unroll
        for (int kk = 0; kk < 2; ++kk) {
            half8 af[4], bf[4];
#pragma unroll
            for (int mi = 0; mi < 4; ++mi)
                af[mi] = *(const half8*)(lA + (wr*64 + mi*16 + lr)*64 + kk*32 + lq*8);
#pragma unroll
            for (int ni = 0; ni < 4; ++ni)
                bf[ni] = *(const half8*)(lB + (wc*64 + ni*16 + lr)*64 + kk*32 + lq*8);
#pragma unroll
            for (int mi = 0; mi < 4; ++mi)
#pragma unroll
                for (int ni = 0; ni < 4; ++ni)
                    acc[mi][ni] = __builtin_amdgcn_mfma_f32_16x16x32_f16(af[mi], bf[ni], acc[mi][ni], 0, 0, 0);
        }
    }

    half_t* Cs = (z == 1) ? Kc : Vc;
#pragma unroll
    for (int mi = 0; mi < 4; ++mi) {
#pragma unroll
        for (int ni = 0; ni < 4; ++ni) {
            int col = n0 + wc*64 + ni*16 + lr;
            float bv4 = bias[col];
#pragma unroll
            for (int j = 0; j < 4; ++j) {
                int row = m0 + wr*64 + mi*16 + lq*4 + j;
                float vv = acc[mi][ni][j] + bv4;
                if (z == 0) {
                    Qh[(size_t)row*DM + col] = (half_t)(vv * qscale);
                } else {
                    int pv = posv[row];
                    if (pv >= 0)
                        Cs[((size_t)((row & ~(SEQ-1)) + pv))*DM + col] = (half_t)vv;
                }
            }
        }
    }
}

// ---------------- V transpose (compacted, linear) into permuted [bh][d][s_perm] ----------------
// key(pos) = 32*(pos>>5) + 16*((pos>>2)&1) + 4*((pos>>3)&3) + (pos&3)
__global__ __launch_bounds__(256) void vtrans_k(
    const half_t* __restrict__ Vc, const int* __restrict__ cnt, half_t* __restrict__ Vt)
{
    __shared__ __align__(16) half_t tile[64][72];
    const int s0 = blockIdx.x * 64;
    const int bh = blockIdx.y;
    const int b = bh >> 4, h = bh & 15;
    const int nc = cnt[b];
    const int t = threadIdx.x;
#pragma unroll
    for (int u = t; u < 512; u += 256) {
        int r = u >> 3, c = (u & 7) * 8;
        half8 hv = {};
        if (s0 + r < nc)
            hv = *(const half8*)(Vc + ((size_t)(b*SEQ + s0 + r))*DM + h*DEPTH + c);
        *(half8*)&tile[r][c] = hv;
    }
    __syncthreads();
#pragma unroll
    for (int u = t; u < 512; u += 256) {
        int d = u >> 3, p0 = (u & 7) * 8;
        half8 hv;
#pragma unroll
        for (int e = 0; e < 8; ++e) {
            int pos = p0 + e;
            int key = 32*(pos>>5) + 16*((pos>>2)&1) + 4*((pos>>3)&3) + (pos&3);
            hv[e] = tile[key][d];
        }
        *(half8*)(Vt + ((size_t)bh*DEPTH + d)*SEQ + s0 + p0) = hv;
    }
}

// ---------------- final projection (A f16 via gload, fp32 out) ----------------
__global__ __launch_bounds__(256) void o_proj(
    const half_t* __restrict__ A, const half_t* __restrict__ Bt,
    const float* __restrict__ bias, float* __restrict__ Cp)
{
    __shared__ __align__(16) half_t lA[128*64];
    __shared__ __align__(16) half_t lB[128*64];
    const int t = threadIdx.x, lane = t & 63, wave = t >> 6;
    const int wr = wave >> 1, wc = wave & 1;
    const int m0 = blockIdx.y * 128, n0 = blockIdx.x * 128;
    const int lr = lane & 15, lq = lane >> 4;
    const int srow = lane >> 3, scol = (lane & 7) * 8;

    f32x4 acc[4][4] = {};

    for (int k0 = 0; k0 < DM; k0 += 64) {
        __syncthreads();
#pragma unroll
        for (int i = 0; i < 4; ++i) {
            const int chunk = wave*4 + i;
            const int row = chunk*8 + srow;
            gload16(A  + (size_t)(m0+row)*DM + k0 + scol, lA + chunk*512);
            gload16(Bt + (size_t)(n0+row)*DM + k0 + scol, lB + chunk*512);
        }
        __syncthreads();

#pragma unroll
        for (int kk = 0; kk < 2; ++kk) {
            half8 af[4], bf[4];
#pragma unroll
            for (int mi = 0; mi < 4; ++mi)
                af[mi] = *(const half8*)(lA + (wr*64 + mi*16 + lr)*64 + kk*32 + lq*8);
#pragma unroll
            for (int ni = 0; ni < 4; ++ni)
                bf[ni] = *(const half8*)(lB + (wc*64 + ni*16 + lr)*64 + kk*32 + lq*8);
#pragma unroll
            for (int mi = 0; mi < 4; ++mi)
#pragma unroll
                for (int ni = 0; ni < 4; ++ni)
                    acc[mi][ni] = __builtin_amdgcn_mfma_f32_16x16x32_f16(af[mi], bf[ni], acc[mi][ni], 0, 0, 0);
        }
    }

#pragma unroll
    for (int mi = 0; mi < 4; ++mi) {
#pragma unroll
        for (int ni = 0; ni < 4; ++ni) {
            int row = m0 + wr*64 + mi*16 + lq*4;
            int col = n0 + wc*64 + ni*16 + lr;
            float bv = bias[col];
#pragma unroll
            for (int j = 0; j < 4; ++j)
                Cp[(size_t)(row+j)*DM + col] = acc[mi][ni][j] + bv;
        }
    }
}

// ---------------- fused flash attention (unchanged from R6) ----------------
__global__ __launch_bounds__(512, 4) void attn_k(
    const half_t* __restrict__ Qh, const half_t* __restrict__ Kc,
    const half_t* __restrict__ Vt, const int* __restrict__ cnt,
    half_t* __restrict__ Oh)
{
    constexpr int KP = 72;
    __shared__ __align__(16) half_t smem[4 * 64 * KP];   // [K0 K1 V0 V1]
    const int t = threadIdx.x;
    const int lane = t & 63, wave = t >> 6;
    const int lr = lane & 15, lq = lane >> 4;
    const int flat = blockIdx.x;             // 0..511
    const int rest = flat >> 3;
    const int qb = rest & 7;
    const int bh = (flat & 7) + 8 * (rest >> 3);
    const int b = bh >> 4, h = bh & 15;
    const int q0 = qb * 256;

    const int nc = cnt[b];
    const int ntk = (nc + 63) >> 6;

    const size_t qbase = ((size_t)(b*SEQ + q0 + wave*32 + lr))*DM + h*DEPTH;
    const half8 aq00 = *(const half8*)(Qh + qbase + lq*8);
    const half8 aq01 = *(const half8*)(Qh + qbase + 32 + lq*8);
    const half8 aq10 = *(const half8*)(Qh + qbase + (size_t)16*DM + lq*8);
    const half8 aq11 = *(const half8*)(Qh + qbase + (size_t)16*DM + 32 + lq*8);

    const int srow = t >> 3, scol = (t & 7) * 8;
    const half_t* gK = Kc + (size_t)(b*SEQ + srow)*DM + h*DEPTH + scol;
    const half_t* gV = Vt + ((size_t)bh*DEPTH + srow)*SEQ + scol;

    half_t* lK = smem;
    half_t* lV = smem + 2*64*KP;

    f32x4 o[2][4] = {};
    f32x4 ol[2] = {};
    half8 onesv;
#pragma unroll
    for (int e = 0; e < 8; ++e) onesv[e] = (half_t)1.0f;

    half8 kreg = *(const half8*)gK;
    half8 vreg = *(const half8*)gV;
    *(half8*)(lK + srow*KP + scol) = kreg;
    *(half8*)(lV + srow*KP + scol) = vreg;
    __syncthreads();

    for (int it = 0; it < ntk; ++it) {
        const int cur = it & 1;
        const int kt = it * 64;
        const bool more = (it + 1 < ntk);
        if (more) {
            kreg = *(const half8*)(gK + (size_t)(it+1)*64*DM);
            vreg = *(const half8*)(gV + (it+1)*64);
        }

        f32x4 s4[2][4] = {};
        __builtin_amdgcn_s_setprio(1);
#pragma unroll
        for (int tt = 0; tt < 4; ++tt) {
            half8 kf = *(const half8*)(lK + cur*64*KP + (tt*16 + lr)*KP + lq*8);
            s4[0][tt] = __builtin_amdgcn_mfma_f32_16x16x32_f16(kf, aq00, s4[0][tt], 0, 0, 0);
            s4[1][tt] = __builtin_amdgcn_mfma_f32_16x16x32_f16(kf, aq10, s4[1][tt], 0, 0, 0);
        }
#pragma unroll
        for (int tt = 0; tt < 4; ++tt) {
            half8 kf = *(const half8*)(lK + cur*64*KP + (tt*16 + lr)*KP + 32 + lq*8);
            s4[0][tt] = __builtin_amdgcn_mfma_f32_16x16x32_f16(kf, aq01, s4[0][tt], 0, 0, 0);
            s4[1][tt] = __builtin_amdgcn_mfma_f32_16x16x32_f16(kf, aq11, s4[1][tt], 0, 0, 0);
        }
        __builtin_amdgcn_s_setprio(0);

        if (kt + 64 <= nc) {
#pragma unroll
            for (int h2 = 0; h2 < 2; ++h2)
#pragma unroll
                for (int tt = 0; tt < 4; ++tt)
#pragma unroll
                    for (int r = 0; r < 4; ++r)
                        s4[h2][tt][r] = __builtin_amdgcn_exp2f(s4[h2][tt][r] - 8.0f);
        } else {
#pragma unroll
            for (int tt = 0; tt < 4; ++tt)
#pragma unroll
                for (int r = 0; r < 4; ++r) {
                    float am = (kt + tt*16 + lq*4 + r < nc) ? -8.0f : -1e30f;
                    s4[0][tt][r] = __builtin_amdgcn_exp2f(s4[0][tt][r] + am);
                    s4[1][tt][r] = __builtin_amdgcn_exp2f(s4[1][tt][r] + am);
                }
        }

        __builtin_amdgcn_s_setprio(1);
#pragma unroll
        for (int kk = 0; kk < 2; ++kk) {
            half8 pk0, pk1;
#pragma unroll
            for (int e = 0; e < 4; ++e) {
                pk0[e]   = (half_t)s4[0][2*kk][e];
                pk0[e+4] = (half_t)s4[0][2*kk+1][e];
                pk1[e]   = (half_t)s4[1][2*kk][e];
                pk1[e+4] = (half_t)s4[1][2*kk+1][e];
            }
#pragma unroll
            for (int ni = 0; ni < 4; ++ni) {
                half8 av = *(const half8*)(lV + cur*64*KP + (ni*16 + lr)*KP + kk*32 + lq*8);
                o[0][ni] = __builtin_amdgcn_mfma_f32_16x16x32_f16(av, pk0, o[0][ni], 0, 0, 0);
                o[1][ni] = __builtin_amdgcn_mfma_f32_16x16x32_f16(av, pk1, o[1][ni], 0, 0, 0);
            }
            ol[0] = __builtin_amdgcn_mfma_f32_16x16x32_f16(onesv, pk0, ol[0], 0, 0, 0);
            ol[1] = __builtin_amdgcn_mfma_f32_16x16x32_f16(onesv, pk1, ol[1], 0, 0, 0);
        }
        __builtin_amdgcn_s_setprio(0);

        if (more) {
            *(half8*)(lK + (cur^1)*64*KP + srow*KP + scol) = kreg;
            *(half8*)(lV + (cur^1)*64*KP + srow*KP + scol) = vreg;
        }
        __syncthreads();
    }

    half_t* pb = smem + wave * 32 * KP;
    float rl0 = 1.0f / ol[0][0];
    float rl1 = 1.0f / ol[1][0];
#pragma unroll
    for (int ni = 0; ni < 4; ++ni)
#pragma unroll
        for (int j = 0; j < 4; ++j) {
            pb[lr*KP + ni*16 + lq*4 + j]        = (half_t)(o[0][ni][j] * rl0);
            pb[(16 + lr)*KP + ni*16 + lq*4 + j] = (half_t)(o[1][ni][j] * rl1);
        }
    __syncthreads();
#pragma unroll
    for (int rr = 0; rr < 4; ++rr) {
        int qq = rr*8 + (lane >> 3);
        int c = (lane & 7) * 8;
        half8 hv = *(const half8*)(pb + qq*KP + c);
        *(half8*)(Oh + (size_t)(b*SEQ + q0 + wave*32 + qq)*DM + h*DEPTH + c) = hv;
    }
}

extern "C" void kernel_launch(void* const* d_in, const int* in_sizes, int n_in,
                              void* d_out, int out_size, void* d_ws, size_t ws_size,
                              hipStream_t stream) {
    (void)in_sizes; (void)n_in; (void)out_size; (void)ws_size;
    const float* v    = (const float*)d_in[0];
    const float* k    = (const float*)d_in[1];
    const float* q    = (const float*)d_in[2];
    const int*   mask = (const int*)  d_in[3];
    const float* wq   = (const float*)d_in[4];
    const float* bq   = (const float*)d_in[5];
    const float* wk   = (const float*)d_in[6];
    const float* bk   = (const float*)d_in[7];
    const float* wv   = (const float*)d_in[8];
    const float* bv   = (const float*)d_in[9];
    const float* wo   = (const float*)d_in[10];
    const float* bo   = (const float*)d_in[11];

    // 72 MB workspace (halves):
    half_t* wT  = (half_t*)d_ws;                 //  8 MB: 4 weights f16^T
    half_t* Qh  = wT + 4ull*1024*1024;           // 16 MB
    half_t* Kc  = Qh + 8ull*1024*1024;           // 16 MB: compacted K
    half_t* Vc  = Kc + 8ull*1024*1024;           // 16 MB: compacted V, later O16
    half_t* Vt  = Vc + 8ull*1024*1024;           // 16 MB: transposed V
    half_t* O16 = Vc;                            // alias (Vc dead after vtrans)

    // posv/cnt in d_out tail (dead before o_proj overwrites d_out)
    int* posv = (int*)((char*)d_out + 32ull*1024*1024 - 65536);
    int* cnt  = posv + 4*SEQ;

    const float qscale = 0.125f * 1.44269504088896340736f;  // depth^-1/2 * log2(e)

    wtrans_k<<<dim3(32,32,4), dim3(32,8), 0, stream>>>(wq, wk, wv, wo, wT);
    midx_k<<<1, 256, 0, stream>>>(mask, posv, cnt, Kc);
    qkv_proj<<<dim3(8,64,3), 256, 0, stream>>>(q, k, v, wT, bq, bk, bv,
                                               posv, Qh, Kc, Vc, qscale);
    vtrans_k<<<dim3(32,64), 256, 0, stream>>>(Vc, cnt, Vt);
    attn_k<<<512, 512, 0, stream>>>(Qh, Kc, Vt, cnt, O16);
    o_proj<<<dim3(8,64), 256, 0, stream>>>(O16, wT + 3ull*1024*1024, bo, (float*)d_out);
}

// Round 8
// 224.636 us; speedup vs baseline: 1.0826x; 1.0826x over previous
//
#include <hip/hip_runtime.h>

typedef _Float16 half_t;
typedef __attribute__((ext_vector_type(8))) _Float16 half8;
typedef __attribute__((ext_vector_type(4))) _Float16 half4;
typedef __attribute__((ext_vector_type(4))) float f32x4;

#define SEQ   2048
#define DM    1024
#define NH    16
#define DEPTH 64

__device__ __forceinline__ void gload16(const void* g, void* l) {
    __builtin_amdgcn_global_load_lds(
        (const __attribute__((address_space(1))) void*)g,
        (__attribute__((address_space(3))) void*)l, 16, 0, 0);
}

// ---------------- weight transpose + fp32->fp16 ----------------
__global__ __launch_bounds__(256) void wtrans_k(
    const float* __restrict__ w0, const float* __restrict__ w1,
    const float* __restrict__ w2, const float* __restrict__ w3,
    half_t* __restrict__ out)
{
    __shared__ float tile[32][33];
    const float* srcs[4] = {w0, w1, w2, w3};
    const float* src = srcs[blockIdx.z];
    half_t* dst = out + (size_t)blockIdx.z * DM * DM;
    int n0 = blockIdx.x * 32, k0 = blockIdx.y * 32;
    int tx = threadIdx.x, ty = threadIdx.y;
#pragma unroll
    for (int i = 0; i < 4; ++i)
        tile[ty + 8*i][tx] = src[(size_t)(k0 + ty + 8*i)*DM + n0 + tx];
    __syncthreads();
#pragma unroll
    for (int i = 0; i < 4; ++i)
        dst[(size_t)(n0 + ty + 8*i)*DM + k0 + tx] = (half_t)tile[tx][ty + 8*i];
}

// ---------------- mask compaction: posv/cnt + Kc pad-zero ----------------
__global__ __launch_bounds__(256) void midx_k(const int* __restrict__ mask,
    int* __restrict__ posv, int* __restrict__ cnt, half_t* __restrict__ Kc)
{
    const int b = threadIdx.x >> 6;
    const int lane = threadIdx.x & 63;
    const int* m = mask + b*SEQ;
    int off = 0;
    for (int c = 0; c < SEQ; c += 64) {
        int keep = (m[c + lane] == 0);
        unsigned long long bal = __ballot(keep);
        int pre = __popcll(bal & ((1ull << lane) - 1ull));
        posv[b*SEQ + c + lane] = keep ? (off + pre) : -1;
        off += __popcll(bal);
    }
    if (lane == 0) cnt[b] = off;
    const int end = (off + 63) & ~63;
    half8 z = {};
    for (int r = off; r < end; ++r) {
#pragma unroll
        for (int c8 = lane; c8 < 128; c8 += 64)
            *(half8*)(Kc + ((size_t)(b*SEQ + r))*DM + c8*8) = z;
    }
}

// ---------------- fused Q/K/V projection, XCD-chunked ----------------
// 1536 blocks 1D. wgid = (flat&7)*192 + flat>>3 ; decode n fastest so the
// 8 blocks sharing an A panel sit on ONE XCD (A fetched from HBM once).
__global__ __launch_bounds__(256) void qkv_proj(
    const float* __restrict__ Aq, const float* __restrict__ Ak, const float* __restrict__ Av,
    const half_t* __restrict__ wT,
    const float* __restrict__ bq, const float* __restrict__ bk, const float* __restrict__ bv,
    const int* __restrict__ posv,
    half_t* __restrict__ Qh, half_t* __restrict__ Kc, half_t* __restrict__ Vc,
    float qscale)
{
    __shared__ __align__(16) half_t lA[128*64];
    __shared__ __align__(16) half_t lB[128*64];
    const int flat = blockIdx.x;                 // 0..1535
    const int wg   = (flat & 7) * 192 + (flat >> 3);
    const int z    = wg >> 9;                    // 0..2
    const int rem  = wg & 511;
    const int n0   = (rem & 7) * 128;            // n fastest within XCD chunk
    const int m0   = (rem >> 3) * 128;

    const float* Af   = (z == 0) ? Aq : (z == 1) ? Ak : Av;
    const half_t* Bt  = wT + (size_t)z * DM * DM;
    const float* bias = (z == 0) ? bq : (z == 1) ? bk : bv;

    const int t = threadIdx.x, lane = t & 63, wave = t >> 6;
    const int wr = wave >> 1, wc = wave & 1;
    const int lr = lane & 15, lq = lane >> 4;
    const int srow = lane >> 3, scol = (lane & 7) * 8;

    f32x4 acc[4][4] = {};

    for (int k0 = 0; k0 < DM; k0 += 64) {
        __syncthreads();
        // B tile via async global->LDS
#pragma unroll
        for (int i = 0; i < 4; ++i) {
            const int chunk = wave*4 + i;                 // wave-uniform
            const int row = chunk*8 + srow;
            gload16(Bt + (size_t)(n0+row)*DM + k0 + scol, lB + chunk*512);
        }
        // A tile: reg-stage f32 -> f16
#pragma unroll
        for (int i = 0; i < 4; ++i) {
            const int g = i*256 + t;
            const int row = g >> 3, sl = (g & 7) * 8;
            const float* ap = Af + (size_t)(m0+row)*DM + k0 + sl;
            float4 lo = *(const float4*)ap;
            float4 hi = *(const float4*)(ap + 4);
            half8 h8;
            h8[0]=(half_t)lo.x; h8[1]=(half_t)lo.y; h8[2]=(half_t)lo.z; h8[3]=(half_t)lo.w;
            h8[4]=(half_t)hi.x; h8[5]=(half_t)hi.y; h8[6]=(half_t)hi.z; h8[7]=(half_t)hi.w;
            *(half8*)(lA + row*64 + sl) = h8;
        }
        __syncthreads();

#pragma unroll
        for (int kk = 0; kk < 2; ++kk) {
            half8 af[4], bf[4];
#pragma unroll
            for (int mi = 0; mi < 4; ++mi)
                af[mi] = *(const half8*)(lA + (wr*64 + mi*16 + lr)*64 + kk*32 + lq*8);
#pragma unroll
            for (int ni = 0; ni < 4; ++ni)
                bf[ni] = *(const half8*)(lB + (wc*64 + ni*16 + lr)*64 + kk*32 + lq*8);
#pragma unroll
            for (int mi = 0; mi < 4; ++mi)
#pragma unroll
                for (int ni = 0; ni < 4; ++ni)
                    acc[mi][ni] = __builtin_amdgcn_mfma_f32_16x16x32_f16(af[mi], bf[ni], acc[mi][ni], 0, 0, 0);
        }
    }

    half_t* Cs = (z == 1) ? Kc : Vc;
#pragma unroll
    for (int mi = 0; mi < 4; ++mi) {
#pragma unroll
        for (int ni = 0; ni < 4; ++ni) {
            int col = n0 + wc*64 + ni*16 + lr;
            float bv4 = bias[col];
#pragma unroll
            for (int j = 0; j < 4; ++j) {
                int row = m0 + wr*64 + mi*16 + lq*4 + j;
                float vv = acc[mi][ni][j] + bv4;
                if (z == 0) {
                    Qh[(size_t)row*DM + col] = (half_t)(vv * qscale);
                } else {
                    int pv = posv[row];
                    if (pv >= 0)
                        Cs[((size_t)((row & ~(SEQ-1)) + pv))*DM + col] = (half_t)vv;
                }
            }
        }
    }
}

// ---------------- V transpose (compacted) into permuted [bh][d][s_perm] ----------------
// key(pos) = 32*(pos>>5) + 16*((pos>>2)&1) + 4*((pos>>3)&3) + (pos&3)
__global__ __launch_bounds__(256) void vtrans_k(
    const half_t* __restrict__ Vc, const int* __restrict__ cnt, half_t* __restrict__ Vt)
{
    __shared__ __align__(16) half_t tile[64][72];
    const int s0 = blockIdx.x * 64;
    const int bh = blockIdx.y;
    const int b = bh >> 4, h = bh & 15;
    const int nc = cnt[b];
    const int t = threadIdx.x;
#pragma unroll
    for (int u = t; u < 512; u += 256) {
        int r = u >> 3, c = (u & 7) * 8;
        half8 hv = {};
        if (s0 + r < nc)
            hv = *(const half8*)(Vc + ((size_t)(b*SEQ + s0 + r))*DM + h*DEPTH + c);
        *(half8*)&tile[r][c] = hv;
    }
    __syncthreads();
#pragma unroll
    for (int u = t; u < 512; u += 256) {
        int d = u >> 3, p0 = (u & 7) * 8;
        half8 hv;
#pragma unroll
        for (int e = 0; e < 8; ++e) {
            int pos = p0 + e;
            int key = 32*(pos>>5) + 16*((pos>>2)&1) + 4*((pos>>3)&3) + (pos&3);
            hv[e] = tile[key][d];
        }
        *(half8*)(Vt + ((size_t)bh*DEPTH + d)*SEQ + s0 + p0) = hv;
    }
}

// ---------------- final projection, XCD-chunked (512 blocks 1D) ----------------
__global__ __launch_bounds__(256) void o_proj(
    const half_t* __restrict__ A, const half_t* __restrict__ Bt,
    const float* __restrict__ bias, float* __restrict__ Cp)
{
    __shared__ __align__(16) half_t lA[128*64];
    __shared__ __align__(16) half_t lB[128*64];
    const int flat = blockIdx.x;                 // 0..511
    const int wg   = (flat & 7) * 64 + (flat >> 3);
    const int n0   = (wg & 7) * 128;
    const int m0   = (wg >> 3) * 128;
    const int t = threadIdx.x, lane = t & 63, wave = t >> 6;
    const int wr = wave >> 1, wc = wave & 1;
    const int lr = lane & 15, lq = lane >> 4;
    const int srow = lane >> 3, scol = (lane & 7) * 8;

    f32x4 acc[4][4] = {};

    for (int k0 = 0; k0 < DM; k0 += 64) {
        __syncthreads();
#pragma unroll
        for (int i = 0; i < 4; ++i) {
            const int chunk = wave*4 + i;
            const int row = chunk*8 + srow;
            gload16(A  + (size_t)(m0+row)*DM + k0 + scol, lA + chunk*512);
            gload16(Bt + (size_t)(n0+row)*DM + k0 + scol, lB + chunk*512);
        }
        __syncthreads();

#pragma unroll
        for (int kk = 0; kk < 2; ++kk) {
            half8 af[4], bf[4];
#pragma unroll
            for (int mi = 0; mi < 4; ++mi)
                af[mi] = *(const half8*)(lA + (wr*64 + mi*16 + lr)*64 + kk*32 + lq*8);
#pragma unroll
            for (int ni = 0; ni < 4; ++ni)
                bf[ni] = *(const half8*)(lB + (wc*64 + ni*16 + lr)*64 + kk*32 + lq*8);
#pragma unroll
            for (int mi = 0; mi < 4; ++mi)
#pragma unroll
                for (int ni = 0; ni < 4; ++ni)
                    acc[mi][ni] = __builtin_amdgcn_mfma_f32_16x16x32_f16(af[mi], bf[ni], acc[mi][ni], 0, 0, 0);
        }
    }

#pragma unroll
    for (int mi = 0; mi < 4; ++mi) {
#pragma unroll
        for (int ni = 0; ni < 4; ++ni) {
            int row = m0 + wr*64 + mi*16 + lq*4;
            int col = n0 + wc*64 + ni*16 + lr;
            float bv = bias[col];
#pragma unroll
            for (int j = 0; j < 4; ++j)
                Cp[(size_t)(row+j)*DM + col] = acc[mi][ni][j] + bv;
        }
    }
}

// ---------------- fused flash attention (unchanged from R6) ----------------
__global__ __launch_bounds__(512, 4) void attn_k(
    const half_t* __restrict__ Qh, const half_t* __restrict__ Kc,
    const half_t* __restrict__ Vt, const int* __restrict__ cnt,
    half_t* __restrict__ Oh)
{
    constexpr int KP = 72;
    __shared__ __align__(16) half_t smem[4 * 64 * KP];   // [K0 K1 V0 V1]
    const int t = threadIdx.x;
    const int lane = t & 63, wave = t >> 6;
    const int lr = lane & 15, lq = lane >> 4;
    const int flat = blockIdx.x;             // 0..511
    const int rest = flat >> 3;
    const int qb = rest & 7;
    const int bh = (flat & 7) + 8 * (rest >> 3);
    const int b = bh >> 4, h = bh & 15;
    const int q0 = qb * 256;

    const int nc = cnt[b];
    const int ntk = (nc + 63) >> 6;

    const size_t qbase = ((size_t)(b*SEQ + q0 + wave*32 + lr))*DM + h*DEPTH;
    const half8 aq00 = *(const half8*)(Qh + qbase + lq*8);
    const half8 aq01 = *(const half8*)(Qh + qbase + 32 + lq*8);
    const half8 aq10 = *(const half8*)(Qh + qbase + (size_t)16*DM + lq*8);
    const half8 aq11 = *(const half8*)(Qh + qbase + (size_t)16*DM + 32 + lq*8);

    const int srow = t >> 3, scol = (t & 7) * 8;
    const half_t* gK = Kc + (size_t)(b*SEQ + srow)*DM + h*DEPTH + scol;
    const half_t* gV = Vt + ((size_t)bh*DEPTH + srow)*SEQ + scol;

    half_t* lK = smem;
    half_t* lV = smem + 2*64*KP;

    f32x4 o[2][4] = {};
    f32x4 ol[2] = {};
    half8 onesv;
#pragma unroll
    for (int e = 0; e < 8; ++e) onesv[e] = (half_t)1.0f;

    half8 kreg = *(const half8*)gK;
    half8 vreg = *(const half8*)gV;
    *(half8*)(lK + srow*KP + scol) = kreg;
    *(half8*)(lV + srow*KP + scol) = vreg;
    __syncthreads();

    for (int it = 0; it < ntk; ++it) {
        const int cur = it & 1;
        const int kt = it * 64;
        const bool more = (it + 1 < ntk);
        if (more) {
            kreg = *(const half8*)(gK + (size_t)(it+1)*64*DM);
            vreg = *(const half8*)(gV + (it+1)*64);
        }

        f32x4 s4[2][4] = {};
        __builtin_amdgcn_s_setprio(1);
#pragma unroll
        for (int tt = 0; tt < 4; ++tt) {
            half8 kf = *(const half8*)(lK + cur*64*KP + (tt*16 + lr)*KP + lq*8);
            s4[0][tt] = __builtin_amdgcn_mfma_f32_16x16x32_f16(kf, aq00, s4[0][tt], 0, 0, 0);
            s4[1][tt] = __builtin_amdgcn_mfma_f32_16x16x32_f16(kf, aq10, s4[1][tt], 0, 0, 0);
        }
#pragma unroll
        for (int tt = 0; tt < 4; ++tt) {
            half8 kf = *(const half8*)(lK + cur*64*KP + (tt*16 + lr)*KP + 32 + lq*8);
            s4[0][tt] = __builtin_amdgcn_mfma_f32_16x16x32_f16(kf, aq01, s4[0][tt], 0, 0, 0);
            s4[1][tt] = __builtin_amdgcn_mfma_f32_16x16x32_f16(kf, aq11, s4[1][tt], 0, 0, 0);
        }
        __builtin_amdgcn_s_setprio(0);

        if (kt + 64 <= nc) {
#pragma unroll
            for (int h2 = 0; h2 < 2; ++h2)
#pragma unroll
                for (int tt = 0; tt < 4; ++tt)
#pragma unroll
                    for (int r = 0; r < 4; ++r)
                        s4[h2][tt][r] = __builtin_amdgcn_exp2f(s4[h2][tt][r] - 8.0f);
        } else {
#pragma unroll
            for (int tt = 0; tt < 4; ++tt)
#pragma unroll
                for (int r = 0; r < 4; ++r) {
                    float am = (kt + tt*16 + lq*4 + r < nc) ? -8.0f : -1e30f;
                    s4[0][tt][r] = __builtin_amdgcn_exp2f(s4[0][tt][r] + am);
                    s4[1][tt][r] = __builtin_amdgcn_exp2f(s4[1][tt][r] + am);
                }
        }

        __builtin_amdgcn_s_setprio(1);
#pragma unroll
        for (int kk = 0; kk < 2; ++kk) {
            half8 pk0, pk1;
#pragma unroll
            for (int e = 0; e < 4; ++e) {
                pk0[e]   = (half_t)s4[0][2*kk][e];
                pk0[e+4] = (half_t)s4[0][2*kk+1][e];
                pk1[e]   = (half_t)s4[1][2*kk][e];
                pk1[e+4] = (half_t)s4[1][2*kk+1][e];
            }
#pragma unroll
            for (int ni = 0; ni < 4; ++ni) {
                half8 av = *(const half8*)(lV + cur*64*KP + (ni*16 + lr)*KP + kk*32 + lq*8);
                o[0][ni] = __builtin_amdgcn_mfma_f32_16x16x32_f16(av, pk0, o[0][ni], 0, 0, 0);
                o[1][ni] = __builtin_amdgcn_mfma_f32_16x16x32_f16(av, pk1, o[1][ni], 0, 0, 0);
            }
            ol[0] = __builtin_amdgcn_mfma_f32_16x16x32_f16(onesv, pk0, ol[0], 0, 0, 0);
            ol[1] = __builtin_amdgcn_mfma_f32_16x16x32_f16(onesv, pk1, ol[1], 0, 0, 0);
        }
        __builtin_amdgcn_s_setprio(0);

        if (more) {
            *(half8*)(lK + (cur^1)*64*KP + srow*KP + scol) = kreg;
            *(half8*)(lV + (cur^1)*64*KP + srow*KP + scol) = vreg;
        }
        __syncthreads();
    }

    half_t* pb = smem + wave * 32 * KP;
    float rl0 = 1.0f / ol[0][0];
    float rl1 = 1.0f / ol[1][0];
#pragma unroll
    for (int ni = 0; ni < 4; ++ni)
#pragma unroll
        for (int j = 0; j < 4; ++j) {
            pb[lr*KP + ni*16 + lq*4 + j]        = (half_t)(o[0][ni][j] * rl0);
            pb[(16 + lr)*KP + ni*16 + lq*4 + j] = (half_t)(o[1][ni][j] * rl1);
        }
    __syncthreads();
#pragma unroll
    for (int rr = 0; rr < 4; ++rr) {
        int qq = rr*8 + (lane >> 3);
        int c = (lane & 7) * 8;
        half8 hv = *(const half8*)(pb + qq*KP + c);
        *(half8*)(Oh + (size_t)(b*SEQ + q0 + wave*32 + qq)*DM + h*DEPTH + c) = hv;
    }
}

extern "C" void kernel_launch(void* const* d_in, const int* in_sizes, int n_in,
                              void* d_out, int out_size, void* d_ws, size_t ws_size,
                              hipStream_t stream) {
    (void)in_sizes; (void)n_in; (void)out_size; (void)ws_size;
    const float* v    = (const float*)d_in[0];
    const float* k    = (const float*)d_in[1];
    const float* q    = (const float*)d_in[2];
    const int*   mask = (const int*)  d_in[3];
    const float* wq   = (const float*)d_in[4];
    const float* bq   = (const float*)d_in[5];
    const float* wk   = (const float*)d_in[6];
    const float* bk   = (const float*)d_in[7];
    const float* wv   = (const float*)d_in[8];
    const float* bv   = (const float*)d_in[9];
    const float* wo   = (const float*)d_in[10];
    const float* bo   = (const float*)d_in[11];

    // 72 MB workspace (halves):
    half_t* wT  = (half_t*)d_ws;                 //  8 MB: 4 weights f16^T
    half_t* Qh  = wT + 4ull*1024*1024;           // 16 MB
    half_t* Kc  = Qh + 8ull*1024*1024;           // 16 MB: compacted K
    half_t* Vc  = Kc + 8ull*1024*1024;           // 16 MB: compacted V, later O16
    half_t* Vt  = Vc + 8ull*1024*1024;           // 16 MB: transposed V
    half_t* O16 = Vc;                            // alias (Vc dead after vtrans)

    // posv/cnt in d_out tail (dead before o_proj overwrites d_out)
    int* posv = (int*)((char*)d_out + 32ull*1024*1024 - 65536);
    int* cnt  = posv + 4*SEQ;

    const float qscale = 0.125f * 1.44269504088896340736f;  // depth^-1/2 * log2(e)

    wtrans_k<<<dim3(32,32,4), dim3(32,8), 0, stream>>>(wq, wk, wv, wo, wT);
    midx_k<<<1, 256, 0, stream>>>(mask, posv, cnt, Kc);
    qkv_proj<<<1536, 256, 0, stream>>>(q, k, v, wT, bq, bk, bv,
                                       posv, Qh, Kc, Vc, qscale);
    vtrans_k<<<dim3(32,64), 256, 0, stream>>>(Vc, cnt, Vt);
    attn_k<<<512, 512, 0, stream>>>(Qh, Kc, Vt, cnt, O16);
    o_proj<<<512, 256, 0, stream>>>(O16, wT + 3ull*1024*1024, bo, (float*)d_out);
}